// Round 4
// baseline (533.879 us; speedup 1.0000x reference)
//
#include <hip/hip_runtime.h>
#include <hip/hip_bf16.h>
#include <math.h>

#define B_ 2
#define T_ 2048
#define D_ 2048
#define H_ 16
#define DH_ 128
#define SEM_ 1024
#define GEO_ 1024
#define NPROJ 6144   // 4*1024 (q/k sem/geo) + 2048 (v)

typedef unsigned short ushort_t;
typedef short bf16x8 __attribute__((ext_vector_type(8)));
typedef float f32x4 __attribute__((ext_vector_type(4)));
typedef unsigned short us4 __attribute__((ext_vector_type(4)));

static __device__ inline ushort_t f2b(float x) {
    __hip_bfloat16 h = __float2bfloat16(x);
    return *reinterpret_cast<ushort_t*>(&h);
}
static __device__ inline float b2f(ushort_t u) {
    union { unsigned int i; float f; } v; v.i = ((unsigned int)u) << 16; return v.f;
}
static __device__ inline void gload_lds16(const ushort_t* g, ushort_t* l) {
    __builtin_amdgcn_global_load_lds(
        (const __attribute__((address_space(1))) void*)g,
        (__attribute__((address_space(3))) void*)l, 16, 0, 0);
}

// ---------------------------------------------------------------------------
// x fp32 -> bf16, 8 elems/thread
// ---------------------------------------------------------------------------
__global__ __launch_bounds__(256) void convert_x(
    const float* __restrict__ x, ushort_t* __restrict__ xh)
{
    size_t i = ((size_t)blockIdx.x * 256 + threadIdx.x) * 8;
    float4 a = *(const float4*)&x[i];
    float4 b = *(const float4*)&x[i + 4];
    bf16x8 o;
    o[0] = (short)f2b(a.x); o[1] = (short)f2b(a.y);
    o[2] = (short)f2b(a.z); o[3] = (short)f2b(a.w);
    o[4] = (short)f2b(b.x); o[5] = (short)f2b(b.y);
    o[6] = (short)f2b(b.z); o[7] = (short)f2b(b.w);
    *(bf16x8*)&xh[i] = o;
}

// ---------------------------------------------------------------------------
// All 6 weight transposes in one launch. z selects the weight.
// W[K=2048][N] fp32 -> dst[N][2048] bf16.
// ---------------------------------------------------------------------------
__global__ __launch_bounds__(256) void transpose_all(
    const float* __restrict__ W0, const float* __restrict__ W1,
    const float* __restrict__ W2, const float* __restrict__ W3,
    const float* __restrict__ W4, const float* __restrict__ W5,
    ushort_t* __restrict__ Wt_all, ushort_t* __restrict__ WoT)
{
    const int z = blockIdx.z;
    const float* W;
    ushort_t* dst;
    int N;
    switch (z) {
        case 0: W = W0; dst = Wt_all;                          N = 1024; break;
        case 1: W = W1; dst = Wt_all + (size_t)1024 * 2048;    N = 1024; break;
        case 2: W = W2; dst = Wt_all + (size_t)2048 * 2048;    N = 1024; break;
        case 3: W = W3; dst = Wt_all + (size_t)3072 * 2048;    N = 1024; break;
        case 4: W = W4; dst = Wt_all + (size_t)4096 * 2048;    N = 2048; break;
        default: W = W5; dst = WoT;                            N = 2048; break;
    }
    const int n0 = blockIdx.x * 32;
    if (n0 >= N) return;
    const int k0 = blockIdx.y * 32;

    __shared__ float tile[32][33];
    const int c = threadIdx.x & 31, r = threadIdx.x >> 5;   // r: 0..7
#pragma unroll
    for (int rr = 0; rr < 32; rr += 8)
        tile[r + rr][c] = W[(size_t)(k0 + r + rr) * N + n0 + c];
    __syncthreads();
#pragma unroll
    for (int rr = 0; rr < 32; rr += 8)
        dst[(size_t)(n0 + r + rr) * 2048 + k0 + c] = f2b(tile[c][r + rr]);
}

// ---------------------------------------------------------------------------
// Projection GEMM — 256x256 tile, BK=64, 8-wave, 8-phase counted-vmcnt
// pipeline (T2 3-bit XOR + T3/T4 + T5), fused RoPE/gate/pack epilogue.
// Round-4: T1 XCD swizzle REVERTED (it streamed all of B through every
// XCD's L2: FETCH 94->176 MB). Natural dispatch order restored.
// Phase ds_reads issued at the tail of the previous phase (round-3 win).
// ---------------------------------------------------------------------------
#define BARS()  { asm volatile("" ::: "memory"); __builtin_amdgcn_s_barrier(); asm volatile("" ::: "memory"); }
#define WL0()   asm volatile("s_waitcnt lgkmcnt(0)" ::: "memory")
#define WV6()   asm volatile("s_waitcnt vmcnt(6)" ::: "memory")

#define LDA8(par, iq, i4, kk) \
    (*(const bf16x8*)&smA[(par)*16384 + (iq)*8192 + aoff + (i4)*1024 + ((kk) ? ca1 : ca0)])
#define LDB8(par, jq, j1, kk) \
    (*(const bf16x8*)&smB[(par)*16384 + (jq)*8192 + boff + (j1)*2048 + ((kk) ? ca1 : ca0)])

#define READ_A(par, iq) \
    aF[0]=LDA8(par,iq,0,0); aF[1]=LDA8(par,iq,0,1); \
    aF[2]=LDA8(par,iq,1,0); aF[3]=LDA8(par,iq,1,1); \
    aF[4]=LDA8(par,iq,2,0); aF[5]=LDA8(par,iq,2,1); \
    aF[6]=LDA8(par,iq,3,0); aF[7]=LDA8(par,iq,3,1);

#define READ_B(par, jq) \
    bF[(jq)*4+0]=LDB8(par,jq,0,0); bF[(jq)*4+1]=LDB8(par,jq,0,1); \
    bF[(jq)*4+2]=LDB8(par,jq,1,0); bF[(jq)*4+3]=LDB8(par,jq,1,1);

#define STAGE_A(h, kt, par) do { \
    const ushort_t* _s = gAbase + (size_t)((h)*128) * 2048 + (kt)*64 + stgoff; \
    ushort_t* _d = smA + (par)*16384 + (h)*8192 + wid*512; \
    gload_lds16(_s, _d); \
    gload_lds16(_s + (size_t)64*2048, _d + 4096); \
} while(0)

#define STAGE_B(h, kt, par) do { \
    const ushort_t* _s = gBbase + (size_t)((h)*128) * 2048 + (kt)*64 + stgoff; \
    ushort_t* _d = smB + (par)*16384 + (h)*8192 + wid*512; \
    gload_lds16(_s, _d); \
    gload_lds16(_s + (size_t)64*2048, _d + 4096); \
} while(0)

#define MM16(iq, jq) do { \
    _Pragma("unroll") \
    for (int i4 = 0; i4 < 4; ++i4) { \
        acc[(iq)*4+i4][(jq)*2+0] = __builtin_amdgcn_mfma_f32_16x16x32_bf16(aF[i4*2+0], bF[(jq)*4+0], acc[(iq)*4+i4][(jq)*2+0], 0, 0, 0); \
        acc[(iq)*4+i4][(jq)*2+0] = __builtin_amdgcn_mfma_f32_16x16x32_bf16(aF[i4*2+1], bF[(jq)*4+1], acc[(iq)*4+i4][(jq)*2+0], 0, 0, 0); \
        acc[(iq)*4+i4][(jq)*2+1] = __builtin_amdgcn_mfma_f32_16x16x32_bf16(aF[i4*2+0], bF[(jq)*4+2], acc[(iq)*4+i4][(jq)*2+1], 0, 0, 0); \
        acc[(iq)*4+i4][(jq)*2+1] = __builtin_amdgcn_mfma_f32_16x16x32_bf16(aF[i4*2+1], bF[(jq)*4+3], acc[(iq)*4+i4][(jq)*2+1], 0, 0, 0); \
    } \
} while(0)

// phase reads are pre-issued at the tail of the previous phase
#define TILE_BODY(par, parn, kt1, kt2) \
    STAGE_A(1, kt1, parn); \
    BARS(); WL0(); \
    __builtin_amdgcn_s_setprio(1); MM16(0, 0); __builtin_amdgcn_s_setprio(0); \
    READ_B(par, 1); \
    BARS(); \
    STAGE_A(0, kt2, par); \
    BARS(); WL0(); \
    __builtin_amdgcn_s_setprio(1); MM16(0, 1); __builtin_amdgcn_s_setprio(0); \
    READ_A(par, 1); \
    BARS(); \
    STAGE_B(0, kt2, par); \
    BARS(); WL0(); \
    __builtin_amdgcn_s_setprio(1); MM16(1, 1); __builtin_amdgcn_s_setprio(0); \
    BARS(); \
    STAGE_B(1, kt2, par); WV6(); \
    BARS(); \
    __builtin_amdgcn_s_setprio(1); MM16(1, 0); __builtin_amdgcn_s_setprio(0); \
    READ_A(parn, 0); READ_B(parn, 0); \
    BARS();

__global__ __launch_bounds__(512, 2) void gemm_proj(
    const ushort_t* __restrict__ A, const ushort_t* __restrict__ Bt,
    const float* __restrict__ gate_logit, const int* __restrict__ pos_off,
    ushort_t* __restrict__ Qh, ushort_t* __restrict__ Kh,
    ushort_t* __restrict__ Vt)
{
    extern __shared__ __align__(16) ushort_t smdyn[];
    ushort_t* smA = smdyn;              // [2 buf][2 half][128][64]
    ushort_t* smB = smdyn + 32768;      // [2 buf][2 half][128][64]

    const int tid  = threadIdx.x;
    const int wid  = tid >> 6, lane = tid & 63;
    const int ln16 = lane & 15, g = lane >> 4;
    const int wm = wid & 1, wn = wid >> 1;
    const int m0 = blockIdx.y * 256, n0 = blockIdx.x * 256;

    // staging: each wave stages an 8-row slab per gload round; global source
    // granule is pre-swizzled by (row&7) so the linear global_load_lds write
    // realizes the 3-bit XOR LDS swizzle.
    const int srow = wid * 8 + (lane >> 3);                    // 0..63
    const int scol = ((lane & 7) ^ (lane >> 3)) * 8;
    const size_t stgoff = (size_t)srow * 2048 + scol;
    const ushort_t* gAbase = A  + (size_t)m0 * 2048;
    const ushort_t* gBbase = Bt + (size_t)n0 * 2048;

    // ds-read swizzled column offsets (elements): granule = (g+4kk)^(ln16&7)
    const int cg0 = ln16 & 7;
    const int ca0 = ((g + 0) ^ cg0) * 8;
    const int ca1 = ((g + 4) ^ cg0) * 8;
    const int aoff = wm * 4096 + ln16 * 64;
    const int boff = (wn >> 1) * 4096 + (wn & 1) * 1024 + ln16 * 64;

    f32x4 acc[8][4];
#pragma unroll
    for (int i = 0; i < 8; ++i)
#pragma unroll
        for (int j = 0; j < 4; ++j) acc[i][j] = (f32x4){0.f, 0.f, 0.f, 0.f};
    bf16x8 aF[8], bF[8];

    // prologue: tile0 complete + first 3 half-tiles of tile1 in flight,
    // then pre-issue tile0's ph1 reads (loop phases expect reads pre-issued)
    STAGE_A(0, 0, 0); STAGE_B(0, 0, 0); STAGE_B(1, 0, 0); STAGE_A(1, 0, 0);
    STAGE_A(0, 1, 1); STAGE_B(0, 1, 1); STAGE_B(1, 1, 1);
    WV6();
    BARS();
    READ_A(0, 0); READ_B(0, 0);

#pragma unroll 1
    for (int t = 0; t < 32; t += 2) {
        const int ka1 = t + 1;
        const int ka2 = (t + 2 < 32) ? t + 2 : 31;
        const int kb1 = ka2;
        const int kb2 = (t + 3 < 32) ? t + 3 : 31;
        TILE_BODY(0, 1, ka1, ka2);
        TILE_BODY(1, 0, kb1, kb2);
    }
    asm volatile("s_waitcnt vmcnt(0) lgkmcnt(0)" ::: "memory");  // drain tails

    // ---- fused epilogue -----------------------------------------------
    const int region = n0 >> 10;           // 0 qs | 1 ks | 2 qg | 3 kg | >=4 v
    const int rbase  = m0 + wm * 64 + g * 4;

    if (region <= 1) {
        ushort_t* dst = (region == 0) ? Qh : Kh;
        const int hb  = ((n0 & 1023) >> 6) + (wn >> 1);
        const int d64 = (wn & 1) * 16 + ln16;
        float sc0 = 1.0f, sc1 = 1.0f;
        if (region == 0) {
            sc0 = 0.25f / (1.0f + __expf(-gate_logit[hb]));      // 2*sig*0.125
            sc1 = 0.25f / (1.0f + __expf(-gate_logit[hb + 2]));
        }
#pragma unroll
        for (int i = 0; i < 8; ++i)
#pragma unroll
            for (int r = 0; r < 4; ++r) {
                int row = rbase + (i >> 2) * 128 + (i & 3) * 16 + r;
                int t = row & (T_ - 1), bb = row >> 11;
                size_t b0 = ((size_t)(bb * H_ + hb)     * T_ + t) * 128;
                size_t b1 = ((size_t)(bb * H_ + hb + 2) * T_ + t) * 128;
                dst[b0 + d64]      = f2b(acc[i][0][r] * sc0);
                dst[b0 + d64 + 32] = f2b(acc[i][1][r] * sc0);
                dst[b1 + d64]      = f2b(acc[i][2][r] * sc1);
                dst[b1 + d64 + 32] = f2b(acc[i][3][r] * sc1);
            }
    } else if (region <= 3) {
        ushort_t* dst = (region == 2) ? Qh : Kh;
        const int hb = ((n0 & 1023) >> 6) + (wn >> 1);
        const int ip = (wn & 1) * 16 + ln16;                    // 0..31
        const float invf = __expf(-0.28782313665087625f * (float)ip);
        const float po = (float)(*pos_off);
        float sc0 = 1.0f, sc1 = 1.0f;
        if (region == 2) {
            sc0 = 0.25f * (1.0f - 1.0f / (1.0f + __expf(-gate_logit[hb])));
            sc1 = 0.25f * (1.0f - 1.0f / (1.0f + __expf(-gate_logit[hb + 2])));
        }
#pragma unroll
        for (int i = 0; i < 8; ++i)
#pragma unroll
            for (int r = 0; r < 4; ++r) {
                int row = rbase + (i >> 2) * 128 + (i & 3) * 16 + r;
                int t = row & (T_ - 1), bb = row >> 11;
                float s, c;
                __sincosf(((float)t + po) * invf, &s, &c);
                size_t b0 = ((size_t)(bb * H_ + hb)     * T_ + t) * 128;
                size_t b1 = ((size_t)(bb * H_ + hb + 2) * T_ + t) * 128;
                float x1 = acc[i][0][r], x2 = acc[i][1][r];
                dst[b0 + 64 + ip] = f2b((x1 * c - x2 * s) * sc0);
                dst[b0 + 96 + ip] = f2b((x2 * c + x1 * s) * sc0);
                x1 = acc[i][2][r]; x2 = acc[i][3][r];
                dst[b1 + 64 + ip] = f2b((x1 * c - x2 * s) * sc1);
                dst[b1 + 96 + ip] = f2b((x2 * c + x1 * s) * sc1);
            }
    } else {
        // V region: pack 4 consecutive-t values (r=0..3) into one 8-B store
        const int hb = (n0 - 4096) >> 7;
        const int db = (wn >> 1) * 64 + (wn & 1) * 16 + ln16;   // 0..127
#pragma unroll
        for (int i = 0; i < 8; ++i) {
            int row0 = rbase + (i >> 2) * 128 + (i & 3) * 16;   // r = 0
            int t0 = row0 & (T_ - 1), bb = row0 >> 11;
#pragma unroll
            for (int j = 0; j < 4; ++j) {
                us4 v;
                v[0] = f2b(acc[i][j][0]); v[1] = f2b(acc[i][j][1]);
                v[2] = f2b(acc[i][j][2]); v[3] = f2b(acc[i][j][3]);
                int hh = hb + (j >> 1);
                int dd = db + (j & 1) * 32;
                *(us4*)&Vt[((size_t)(bb * H_ + hh) * DH_ + dd) * T_ + t0] = v;
            }
        }
    }
}

// ---------------------------------------------------------------------------
// Generic bf16 MFMA GEMM (m97 structure), fp32 out — used for Wo.
// ---------------------------------------------------------------------------
__global__ __launch_bounds__(256) void gemm_bt_f32(
    const ushort_t* __restrict__ A, const ushort_t* __restrict__ Bt,
    float* __restrict__ C, int M, int N, int K)
{
    __shared__ ushort_t As[128 * 32];
    __shared__ ushort_t Bs[128 * 32];

    const int tid  = threadIdx.x;
    const int wid  = tid >> 6, lane = tid & 63;
    const int ln16 = lane & 15, g = lane >> 4;
    const int wm = wid & 1, wn = wid >> 1;
    const int m0 = blockIdx.y * 128, n0 = blockIdx.x * 128;

    const int lrow = lane >> 2;
    const int lc8  = (lane & 3) * 8;
    const ushort_t* gA = A  + (size_t)(m0 + wid * 32 + lrow) * K + lc8;
    const ushort_t* gB = Bt + (size_t)(n0 + wid * 32 + lrow) * K + lc8;
    ushort_t* lA = As + wid * 1024;
    ushort_t* lB = Bs + wid * 1024;
    const size_t K16 = (size_t)16 * K;

    f32x4 acc[4][4];
#pragma unroll
    for (int i = 0; i < 4; ++i)
#pragma unroll
        for (int j = 0; j < 4; ++j) acc[i][j] = (f32x4){0.f, 0.f, 0.f, 0.f};

    for (int k0 = 0; k0 < K; k0 += 32) {
        __syncthreads();
        gload_lds16(gA,       lA);
        gload_lds16(gA + K16, lA + 512);
        gload_lds16(gB,       lB);
        gload_lds16(gB + K16, lB + 512);
        gA += 32; gB += 32;
        __syncthreads();

        bf16x8 af[4], bfr[4];
#pragma unroll
        for (int i = 0; i < 4; ++i)
            af[i] = *(const bf16x8*)&As[(wm * 64 + i * 16 + ln16) * 32 + g * 8];
#pragma unroll
        for (int j = 0; j < 4; ++j)
            bfr[j] = *(const bf16x8*)&Bs[(wn * 64 + j * 16 + ln16) * 32 + g * 8];
#pragma unroll
        for (int i = 0; i < 4; ++i)
#pragma unroll
            for (int j = 0; j < 4; ++j)
                acc[i][j] = __builtin_amdgcn_mfma_f32_16x16x32_bf16(
                    af[i], bfr[j], acc[i][j], 0, 0, 0);
    }

#pragma unroll
    for (int i = 0; i < 4; ++i)
#pragma unroll
        for (int j = 0; j < 4; ++j)
#pragma unroll
            for (int r = 0; r < 4; ++r) {
                int row = m0 + wm * 64 + i * 16 + g * 4 + r;
                int col = n0 + wn * 64 + j * 16 + ln16;
                C[(size_t)row * N + col] = acc[i][j][r];
            }
}

// ---------------------------------------------------------------------------
// Flash attention — round-4: NO K/V LDS staging (K/V per (b,h) is 1 MB,
// L2/L3-resident and shared by 16 blocks — staging was pure overhead).
// Fragments are loaded global->register directly in MFMA layout:
//   bk (c2,half):  K[kt + half*16 + ln16][c2*32 + g*8]   (16 B/lane)
//   bv (cdv):      Vt[cdv*16 + ln16][kt + g*8]           (16 B/lane)
// K double-buffered across kb iterations; V + next-K issued before QK^T so
// ~16 loads stay in flight (compiler counted-vmcnt). ZERO barriers in the
// K-loop; Pl is wave-private (lgkmcnt only). Per-wave loop bound (causal).
// ---------------------------------------------------------------------------
#define P_PITCH  40

__global__ __launch_bounds__(256) void flash_attn(
    const ushort_t* __restrict__ Qh,
    const ushort_t* __restrict__ Kh,
    const ushort_t* __restrict__ Vt,     // [bh][128][T]
    ushort_t* __restrict__ aoh)          // [b*T+t][2048] bf16
{
    __shared__ ushort_t Pl[4 * 16 * P_PITCH];

    const int tid  = threadIdx.x;
    const int wid  = tid >> 6, lane = tid & 63;
    const int ln16 = lane & 15, g = lane >> 4;
    const int p    = blockIdx.x;         // pair index 0..15
    const int h  = blockIdx.y, b = blockIdx.z;
    const int bh = b * H_ + h;

    const ushort_t* Kbase = Kh + (size_t)bh * T_ * 128;
    const ushort_t* Vbase = Vt + (size_t)bh * 128 * T_;
    ushort_t* Pw = Pl + wid * 16 * P_PITCH;

    // per-lane fragment base offsets
    const ushort_t* K0p = Kbase + (size_t)ln16 * 128 + g * 8;        // + kt*128 + c2*32
    const ushort_t* K1p = K0p + 16 * 128;
    const ushort_t* Vp  = Vbase + (size_t)ln16 * T_ + g * 8;         // + cdv*16*T_ + kt

    bf16x8 bones;
    {
        short o = (ln16 == 0) ? (short)0x3F80 : (short)0;
#pragma unroll
        for (int j = 0; j < 8; ++j) bones[j] = o;
    }

#pragma unroll 1
    for (int ti = 0; ti < 2; ++ti) {
        const int qt = ti ? (31 - p) : p;
        const int q0 = qt * 64;
        const int qw = q0 + wid * 16;

        bf16x8 aq[4];
        {
            const ushort_t* qrow = Qh + ((size_t)bh * T_ + qw + ln16) * 128;
#pragma unroll
            for (int c2 = 0; c2 < 4; ++c2)
                aq[c2] = *(const bf16x8*)(qrow + c2 * 32 + g * 8);
        }

        f32x4 acc[8];
#pragma unroll
        for (int i = 0; i < 8; ++i) acc[i] = (f32x4){0.f, 0.f, 0.f, 0.f};
        f32x4 acc_l = (f32x4){0.f, 0.f, 0.f, 0.f};

        const int qmax = qw + 15;
        const int kbw  = qmax >> 5;          // last K-tile index for this wave

        // preload K[0] fragments
        bf16x8 kA0[4], kA1[4];
#pragma unroll
        for (int c2 = 0; c2 < 4; ++c2) {
            kA0[c2] = *(const bf16x8*)(K0p + c2 * 32);
            kA1[c2] = *(const bf16x8*)(K1p + c2 * 32);
        }

#pragma unroll 1
        for (int kb = 0; kb <= kbw; ++kb) {
            const int kt = kb * 32;

            // issue V[kb] loads
            bf16x8 bv[8];
#pragma unroll
            for (int cdv = 0; cdv < 8; ++cdv)
                bv[cdv] = *(const bf16x8*)(Vp + (size_t)(cdv * 16) * T_ + kt);

            // issue K[kb+1] loads (wave-uniform guard)
            bf16x8 kN0[4], kN1[4];
            if (kb < kbw) {
                const size_t ko = (size_t)(kt + 32) * 128;
#pragma unroll
                for (int c2 = 0; c2 < 4; ++c2) {
                    kN0[c2] = *(const bf16x8*)(K0p + ko + c2 * 32);
                    kN1[c2] = *(const bf16x8*)(K1p + ko + c2 * 32);
                }
            }

            // QK^T with resident K[kb]
            f32x4 s0 = (f32x4){0.f, 0.f, 0.f, 0.f};
            f32x4 s1 = (f32x4){0.f, 0.f, 0.f, 0.f};
            __builtin_amdgcn_s_setprio(1);
#pragma unroll
            for (int c2 = 0; c2 < 4; ++c2) {
                s0 = __builtin_amdgcn_mfma_f32_16x16x32_bf16(aq[c2], kA0[c2], s0, 0, 0, 0);
                s1 = __builtin_amdgcn_mfma_f32_16x16x32_bf16(aq[c2], kA1[c2], s1, 0, 0, 0);
            }
            __builtin_amdgcn_s_setprio(0);

            const bool diag = (kt + 31 > qw);
#pragma unroll
            for (int r2 = 0; r2 < 4; ++r2) {
                float e0 = __expf(s0[r2] - 12.0f);
                float e1 = __expf(s1[r2] - 12.0f);
                if (diag) {
                    int qr = qw + g * 4 + r2;
                    e0 = (kt + ln16      > qr) ? 0.0f : e0;
                    e1 = (kt + 16 + ln16 > qr) ? 0.0f : e1;
                }
                int prow = g * 4 + r2;
                Pw[prow * P_PITCH + ln16]      = f2b(e0);
                Pw[prow * P_PITCH + 16 + ln16] = f2b(e1);
            }
            __asm__ volatile("s_waitcnt lgkmcnt(0)" ::: "memory");
            bf16x8 ap = *(const bf16x8*)&Pw[ln16 * P_PITCH + g * 8];

            __builtin_amdgcn_s_setprio(1);
#pragma unroll
            for (int cdv = 0; cdv < 8; ++cdv)
                acc[cdv] = __builtin_amdgcn_mfma_f32_16x16x32_bf16(ap, bv[cdv], acc[cdv], 0, 0, 0);
            acc_l = __builtin_amdgcn_mfma_f32_16x16x32_bf16(ap, bones, acc_l, 0, 0, 0);
            __builtin_amdgcn_s_setprio(0);

            // rotate K buffers (static indices)
            if (kb < kbw) {
#pragma unroll
                for (int c2 = 0; c2 < 4; ++c2) {
                    kA0[c2] = kN0[c2];
                    kA1[c2] = kN1[c2];
                }
            }
        }

        float invl[4];
#pragma unroll
        for (int r2 = 0; r2 < 4; ++r2)
            invl[r2] = 1.0f / __shfl(acc_l[r2], lane & 48);
#pragma unroll
        for (int cdv = 0; cdv < 8; ++cdv)
#pragma unroll
            for (int r2 = 0; r2 < 4; ++r2) {
                int qr = qw + g * 4 + r2;
                aoh[((size_t)b * T_ + qr) * D_ + h * DH_ + cdv * 16 + ln16] =
                    f2b(acc[cdv][r2] * invl[r2]);
            }
    }
}

// ---------------------------------------------------------------------------
extern "C" void kernel_launch(void* const* d_in, const int* in_sizes, int n_in,
                              void* d_out, int out_size, void* d_ws, size_t ws_size,
                              hipStream_t stream)
{
    const float* x       = (const float*)d_in[0];
    const float* Wq_sem  = (const float*)d_in[1];
    const float* Wk_sem  = (const float*)d_in[2];
    const float* Wq_geo  = (const float*)d_in[3];
    const float* Wk_geo  = (const float*)d_in[4];
    const float* Wv      = (const float*)d_in[5];
    const float* Wo      = (const float*)d_in[6];
    const float* gate    = (const float*)d_in[7];
    const int*   pos_off = (const int*)d_in[8];
    float* out = (float*)d_out;

    const int M = B_ * T_;                       // 4096
    char* ws = (char*)d_ws;
    ushort_t* xh     = (ushort_t*)(ws);                          // [4096][2048] 16MB
    ushort_t* aoh    = xh;                                       // reuse after proj
    ushort_t* Wt_all = (ushort_t*)(ws + (size_t)16 * 1048576);   // [6144][2048] 24MB
    ushort_t* WoT    = (ushort_t*)(ws + (size_t)40 * 1048576);   // [2048][2048] 8MB
    ushort_t* Qh     = (ushort_t*)(ws + (size_t)48 * 1048576);   // 16MB
    ushort_t* Kh     = (ushort_t*)(ws + (size_t)64 * 1048576);   // 16MB
    ushort_t* Vt     = (ushort_t*)(ws + (size_t)80 * 1048576);   // 16MB

    dim3 blk(256);

    convert_x<<<(M * D_) / (256 * 8), blk, 0, stream>>>(x, xh);
    transpose_all<<<dim3(64, 64, 6), blk, 0, stream>>>(
        Wq_sem, Wk_sem, Wq_geo, Wk_geo, Wv, Wo, Wt_all, WoT);

    // 256x256-tile 8-phase pipeline needs 128 KiB dynamic LDS
    hipFuncSetAttribute((const void*)gemm_proj,
                        hipFuncAttributeMaxDynamicSharedMemorySize, 131072);
    gemm_proj<<<dim3(NPROJ / 256, M / 256), dim3(512), 131072, stream>>>(
        xh, Wt_all, gate, pos_off, Qh, Kh, Vt);

    flash_attn<<<dim3(16, H_, B_), blk, 0, stream>>>(Qh, Kh, Vt, aoh);

    gemm_bt_f32<<<dim3(D_ / 128, M / 128), blk, 0, stream>>>(
        aoh, WoT, out, M, D_, D_);
}

// Round 5
// 391.138 us; speedup vs baseline: 1.3649x; 1.3649x over previous
//
#include <hip/hip_runtime.h>
#include <hip/hip_bf16.h>
#include <math.h>

#define B_ 2
#define T_ 2048
#define D_ 2048
#define H_ 16
#define DH_ 128
#define SEM_ 1024
#define GEO_ 1024
#define NPROJ 6144   // 4*1024 (q/k sem/geo) + 2048 (v)

typedef unsigned short ushort_t;
typedef short bf16x8 __attribute__((ext_vector_type(8)));
typedef float f32x4 __attribute__((ext_vector_type(4)));
typedef unsigned short us4 __attribute__((ext_vector_type(4)));

static __device__ inline ushort_t f2b(float x) {
    __hip_bfloat16 h = __float2bfloat16(x);
    return *reinterpret_cast<ushort_t*>(&h);
}
static __device__ inline float b2f(ushort_t u) {
    union { unsigned int i; float f; } v; v.i = ((unsigned int)u) << 16; return v.f;
}
static __device__ inline void gload_lds16(const ushort_t* g, ushort_t* l) {
    __builtin_amdgcn_global_load_lds(
        (const __attribute__((address_space(1))) void*)g,
        (__attribute__((address_space(3))) void*)l, 16, 0, 0);
}

// ---------------------------------------------------------------------------
// x fp32 -> bf16, 8 elems/thread
// ---------------------------------------------------------------------------
__global__ __launch_bounds__(256) void convert_x(
    const float* __restrict__ x, ushort_t* __restrict__ xh)
{
    size_t i = ((size_t)blockIdx.x * 256 + threadIdx.x) * 8;
    float4 a = *(const float4*)&x[i];
    float4 b = *(const float4*)&x[i + 4];
    bf16x8 o;
    o[0] = (short)f2b(a.x); o[1] = (short)f2b(a.y);
    o[2] = (short)f2b(a.z); o[3] = (short)f2b(a.w);
    o[4] = (short)f2b(b.x); o[5] = (short)f2b(b.y);
    o[6] = (short)f2b(b.z); o[7] = (short)f2b(b.w);
    *(bf16x8*)&xh[i] = o;
}

// ---------------------------------------------------------------------------
// All 6 weight transposes in one launch. z selects the weight.
// W[K=2048][N] fp32 -> dst[N][2048] bf16.
// ---------------------------------------------------------------------------
__global__ __launch_bounds__(256) void transpose_all(
    const float* __restrict__ W0, const float* __restrict__ W1,
    const float* __restrict__ W2, const float* __restrict__ W3,
    const float* __restrict__ W4, const float* __restrict__ W5,
    ushort_t* __restrict__ Wt_all, ushort_t* __restrict__ WoT)
{
    const int z = blockIdx.z;
    const float* W;
    ushort_t* dst;
    int N;
    switch (z) {
        case 0: W = W0; dst = Wt_all;                          N = 1024; break;
        case 1: W = W1; dst = Wt_all + (size_t)1024 * 2048;    N = 1024; break;
        case 2: W = W2; dst = Wt_all + (size_t)2048 * 2048;    N = 1024; break;
        case 3: W = W3; dst = Wt_all + (size_t)3072 * 2048;    N = 1024; break;
        case 4: W = W4; dst = Wt_all + (size_t)4096 * 2048;    N = 2048; break;
        default: W = W5; dst = WoT;                            N = 2048; break;
    }
    const int n0 = blockIdx.x * 32;
    if (n0 >= N) return;
    const int k0 = blockIdx.y * 32;

    __shared__ float tile[32][33];
    const int c = threadIdx.x & 31, r = threadIdx.x >> 5;   // r: 0..7
#pragma unroll
    for (int rr = 0; rr < 32; rr += 8)
        tile[r + rr][c] = W[(size_t)(k0 + r + rr) * N + n0 + c];
    __syncthreads();
#pragma unroll
    for (int rr = 0; rr < 32; rr += 8)
        dst[(size_t)(n0 + r + rr) * 2048 + k0 + c] = f2b(tile[c][r + rr]);
}

// ---------------------------------------------------------------------------
// Projection GEMM — 256x256 tile, BK=64, 8-wave, 8-phase counted-vmcnt
// pipeline (T2 3-bit XOR + T3/T4 + T5), fused RoPE/gate/pack epilogue.
// Phase ds_reads issued at the tail of the previous phase (round-3 win).
// T1 XCD swizzle reverted (round-4): natural dispatch order.
// ---------------------------------------------------------------------------
#define BARS()  { asm volatile("" ::: "memory"); __builtin_amdgcn_s_barrier(); asm volatile("" ::: "memory"); }
#define WL0()   asm volatile("s_waitcnt lgkmcnt(0)" ::: "memory")
#define WV6()   asm volatile("s_waitcnt vmcnt(6)" ::: "memory")

#define LDA8(par, iq, i4, kk) \
    (*(const bf16x8*)&smA[(par)*16384 + (iq)*8192 + aoff + (i4)*1024 + ((kk) ? ca1 : ca0)])
#define LDB8(par, jq, j1, kk) \
    (*(const bf16x8*)&smB[(par)*16384 + (jq)*8192 + boff + (j1)*2048 + ((kk) ? ca1 : ca0)])

#define READ_A(par, iq) \
    aF[0]=LDA8(par,iq,0,0); aF[1]=LDA8(par,iq,0,1); \
    aF[2]=LDA8(par,iq,1,0); aF[3]=LDA8(par,iq,1,1); \
    aF[4]=LDA8(par,iq,2,0); aF[5]=LDA8(par,iq,2,1); \
    aF[6]=LDA8(par,iq,3,0); aF[7]=LDA8(par,iq,3,1);

#define READ_B(par, jq) \
    bF[(jq)*4+0]=LDB8(par,jq,0,0); bF[(jq)*4+1]=LDB8(par,jq,0,1); \
    bF[(jq)*4+2]=LDB8(par,jq,1,0); bF[(jq)*4+3]=LDB8(par,jq,1,1);

#define STAGE_A(h, kt, par) do { \
    const ushort_t* _s = gAbase + (size_t)((h)*128) * 2048 + (kt)*64 + stgoff; \
    ushort_t* _d = smA + (par)*16384 + (h)*8192 + wid*512; \
    gload_lds16(_s, _d); \
    gload_lds16(_s + (size_t)64*2048, _d + 4096); \
} while(0)

#define STAGE_B(h, kt, par) do { \
    const ushort_t* _s = gBbase + (size_t)((h)*128) * 2048 + (kt)*64 + stgoff; \
    ushort_t* _d = smB + (par)*16384 + (h)*8192 + wid*512; \
    gload_lds16(_s, _d); \
    gload_lds16(_s + (size_t)64*2048, _d + 4096); \
} while(0)

#define MM16(iq, jq) do { \
    _Pragma("unroll") \
    for (int i4 = 0; i4 < 4; ++i4) { \
        acc[(iq)*4+i4][(jq)*2+0] = __builtin_amdgcn_mfma_f32_16x16x32_bf16(aF[i4*2+0], bF[(jq)*4+0], acc[(iq)*4+i4][(jq)*2+0], 0, 0, 0); \
        acc[(iq)*4+i4][(jq)*2+0] = __builtin_amdgcn_mfma_f32_16x16x32_bf16(aF[i4*2+1], bF[(jq)*4+1], acc[(iq)*4+i4][(jq)*2+0], 0, 0, 0); \
        acc[(iq)*4+i4][(jq)*2+1] = __builtin_amdgcn_mfma_f32_16x16x32_bf16(aF[i4*2+0], bF[(jq)*4+2], acc[(iq)*4+i4][(jq)*2+1], 0, 0, 0); \
        acc[(iq)*4+i4][(jq)*2+1] = __builtin_amdgcn_mfma_f32_16x16x32_bf16(aF[i4*2+1], bF[(jq)*4+3], acc[(iq)*4+i4][(jq)*2+1], 0, 0, 0); \
    } \
} while(0)

// phase reads are pre-issued at the tail of the previous phase
#define TILE_BODY(par, parn, kt1, kt2) \
    STAGE_A(1, kt1, parn); \
    BARS(); WL0(); \
    __builtin_amdgcn_s_setprio(1); MM16(0, 0); __builtin_amdgcn_s_setprio(0); \
    READ_B(par, 1); \
    BARS(); \
    STAGE_A(0, kt2, par); \
    BARS(); WL0(); \
    __builtin_amdgcn_s_setprio(1); MM16(0, 1); __builtin_amdgcn_s_setprio(0); \
    READ_A(par, 1); \
    BARS(); \
    STAGE_B(0, kt2, par); \
    BARS(); WL0(); \
    __builtin_amdgcn_s_setprio(1); MM16(1, 1); __builtin_amdgcn_s_setprio(0); \
    BARS(); \
    STAGE_B(1, kt2, par); WV6(); \
    BARS(); \
    __builtin_amdgcn_s_setprio(1); MM16(1, 0); __builtin_amdgcn_s_setprio(0); \
    READ_A(parn, 0); READ_B(parn, 0); \
    BARS();

__global__ __launch_bounds__(512, 2) void gemm_proj(
    const ushort_t* __restrict__ A, const ushort_t* __restrict__ Bt,
    const float* __restrict__ gate_logit, const int* __restrict__ pos_off,
    ushort_t* __restrict__ Qh, ushort_t* __restrict__ Kh,
    ushort_t* __restrict__ Vt)
{
    extern __shared__ __align__(16) ushort_t smdyn[];
    ushort_t* smA = smdyn;              // [2 buf][2 half][128][64]
    ushort_t* smB = smdyn + 32768;      // [2 buf][2 half][128][64]

    const int tid  = threadIdx.x;
    const int wid  = tid >> 6, lane = tid & 63;
    const int ln16 = lane & 15, g = lane >> 4;
    const int wm = wid & 1, wn = wid >> 1;
    const int m0 = blockIdx.y * 256, n0 = blockIdx.x * 256;

    // staging: each wave stages an 8-row slab per gload round; global source
    // granule is pre-swizzled by (row&7) so the linear global_load_lds write
    // realizes the 3-bit XOR LDS swizzle.
    const int srow = wid * 8 + (lane >> 3);                    // 0..63
    const int scol = ((lane & 7) ^ (lane >> 3)) * 8;
    const size_t stgoff = (size_t)srow * 2048 + scol;
    const ushort_t* gAbase = A  + (size_t)m0 * 2048;
    const ushort_t* gBbase = Bt + (size_t)n0 * 2048;

    // ds-read swizzled column offsets (elements): granule = (g+4kk)^(ln16&7)
    const int cg0 = ln16 & 7;
    const int ca0 = ((g + 0) ^ cg0) * 8;
    const int ca1 = ((g + 4) ^ cg0) * 8;
    const int aoff = wm * 4096 + ln16 * 64;
    const int boff = (wn >> 1) * 4096 + (wn & 1) * 1024 + ln16 * 64;

    f32x4 acc[8][4];
#pragma unroll
    for (int i = 0; i < 8; ++i)
#pragma unroll
        for (int j = 0; j < 4; ++j) acc[i][j] = (f32x4){0.f, 0.f, 0.f, 0.f};
    bf16x8 aF[8], bF[8];

    // prologue: tile0 complete + first 3 half-tiles of tile1 in flight,
    // then pre-issue tile0's ph1 reads (loop phases expect reads pre-issued)
    STAGE_A(0, 0, 0); STAGE_B(0, 0, 0); STAGE_B(1, 0, 0); STAGE_A(1, 0, 0);
    STAGE_A(0, 1, 1); STAGE_B(0, 1, 1); STAGE_B(1, 1, 1);
    WV6();
    BARS();
    READ_A(0, 0); READ_B(0, 0);

#pragma unroll 1
    for (int t = 0; t < 32; t += 2) {
        const int ka1 = t + 1;
        const int ka2 = (t + 2 < 32) ? t + 2 : 31;
        const int kb1 = ka2;
        const int kb2 = (t + 3 < 32) ? t + 3 : 31;
        TILE_BODY(0, 1, ka1, ka2);
        TILE_BODY(1, 0, kb1, kb2);
    }
    asm volatile("s_waitcnt vmcnt(0) lgkmcnt(0)" ::: "memory");  // drain tails

    // ---- fused epilogue -----------------------------------------------
    const int region = n0 >> 10;           // 0 qs | 1 ks | 2 qg | 3 kg | >=4 v
    const int rbase  = m0 + wm * 64 + g * 4;

    if (region <= 1) {
        ushort_t* dst = (region == 0) ? Qh : Kh;
        const int hb  = ((n0 & 1023) >> 6) + (wn >> 1);
        const int d64 = (wn & 1) * 16 + ln16;
        float sc0 = 1.0f, sc1 = 1.0f;
        if (region == 0) {
            sc0 = 0.25f / (1.0f + __expf(-gate_logit[hb]));      // 2*sig*0.125
            sc1 = 0.25f / (1.0f + __expf(-gate_logit[hb + 2]));
        }
#pragma unroll
        for (int i = 0; i < 8; ++i)
#pragma unroll
            for (int r = 0; r < 4; ++r) {
                int row = rbase + (i >> 2) * 128 + (i & 3) * 16 + r;
                int t = row & (T_ - 1), bb = row >> 11;
                size_t b0 = ((size_t)(bb * H_ + hb)     * T_ + t) * 128;
                size_t b1 = ((size_t)(bb * H_ + hb + 2) * T_ + t) * 128;
                dst[b0 + d64]      = f2b(acc[i][0][r] * sc0);
                dst[b0 + d64 + 32] = f2b(acc[i][1][r] * sc0);
                dst[b1 + d64]      = f2b(acc[i][2][r] * sc1);
                dst[b1 + d64 + 32] = f2b(acc[i][3][r] * sc1);
            }
    } else if (region <= 3) {
        ushort_t* dst = (region == 2) ? Qh : Kh;
        const int hb = ((n0 & 1023) >> 6) + (wn >> 1);
        const int ip = (wn & 1) * 16 + ln16;                    // 0..31
        const float invf = __expf(-0.28782313665087625f * (float)ip);
        const float po = (float)(*pos_off);
        float sc0 = 1.0f, sc1 = 1.0f;
        if (region == 2) {
            sc0 = 0.25f * (1.0f - 1.0f / (1.0f + __expf(-gate_logit[hb])));
            sc1 = 0.25f * (1.0f - 1.0f / (1.0f + __expf(-gate_logit[hb + 2])));
        }
#pragma unroll
        for (int i = 0; i < 8; ++i)
#pragma unroll
            for (int r = 0; r < 4; ++r) {
                int row = rbase + (i >> 2) * 128 + (i & 3) * 16 + r;
                int t = row & (T_ - 1), bb = row >> 11;
                float s, c;
                __sincosf(((float)t + po) * invf, &s, &c);
                size_t b0 = ((size_t)(bb * H_ + hb)     * T_ + t) * 128;
                size_t b1 = ((size_t)(bb * H_ + hb + 2) * T_ + t) * 128;
                float x1 = acc[i][0][r], x2 = acc[i][1][r];
                dst[b0 + 64 + ip] = f2b((x1 * c - x2 * s) * sc0);
                dst[b0 + 96 + ip] = f2b((x2 * c + x1 * s) * sc0);
                x1 = acc[i][2][r]; x2 = acc[i][3][r];
                dst[b1 + 64 + ip] = f2b((x1 * c - x2 * s) * sc1);
                dst[b1 + 96 + ip] = f2b((x2 * c + x1 * s) * sc1);
            }
    } else {
        // V region: pack 4 consecutive-t values (r=0..3) into one 8-B store
        const int hb = (n0 - 4096) >> 7;
        const int db = (wn >> 1) * 64 + (wn & 1) * 16 + ln16;   // 0..127
#pragma unroll
        for (int i = 0; i < 8; ++i) {
            int row0 = rbase + (i >> 2) * 128 + (i & 3) * 16;   // r = 0
            int t0 = row0 & (T_ - 1), bb = row0 >> 11;
#pragma unroll
            for (int j = 0; j < 4; ++j) {
                us4 v;
                v[0] = f2b(acc[i][j][0]); v[1] = f2b(acc[i][j][1]);
                v[2] = f2b(acc[i][j][2]); v[3] = f2b(acc[i][j][3]);
                int hh = hb + (j >> 1);
                int dd = db + (j & 1) * 32;
                *(us4*)&Vt[((size_t)(bb * H_ + hh) * DH_ + dd) * T_ + t0] = v;
            }
        }
    }
}

// ---------------------------------------------------------------------------
// Generic bf16 MFMA GEMM (m97 structure), fp32 out — used for Wo.
// ---------------------------------------------------------------------------
__global__ __launch_bounds__(256) void gemm_bt_f32(
    const ushort_t* __restrict__ A, const ushort_t* __restrict__ Bt,
    float* __restrict__ C, int M, int N, int K)
{
    __shared__ ushort_t As[128 * 32];
    __shared__ ushort_t Bs[128 * 32];

    const int tid  = threadIdx.x;
    const int wid  = tid >> 6, lane = tid & 63;
    const int ln16 = lane & 15, g = lane >> 4;
    const int wm = wid & 1, wn = wid >> 1;
    const int m0 = blockIdx.y * 128, n0 = blockIdx.x * 128;

    const int lrow = lane >> 2;
    const int lc8  = (lane & 3) * 8;
    const ushort_t* gA = A  + (size_t)(m0 + wid * 32 + lrow) * K + lc8;
    const ushort_t* gB = Bt + (size_t)(n0 + wid * 32 + lrow) * K + lc8;
    ushort_t* lA = As + wid * 1024;
    ushort_t* lB = Bs + wid * 1024;
    const size_t K16 = (size_t)16 * K;

    f32x4 acc[4][4];
#pragma unroll
    for (int i = 0; i < 4; ++i)
#pragma unroll
        for (int j = 0; j < 4; ++j) acc[i][j] = (f32x4){0.f, 0.f, 0.f, 0.f};

    for (int k0 = 0; k0 < K; k0 += 32) {
        __syncthreads();
        gload_lds16(gA,       lA);
        gload_lds16(gA + K16, lA + 512);
        gload_lds16(gB,       lB);
        gload_lds16(gB + K16, lB + 512);
        gA += 32; gB += 32;
        __syncthreads();

        bf16x8 af[4], bfr[4];
#pragma unroll
        for (int i = 0; i < 4; ++i)
            af[i] = *(const bf16x8*)&As[(wm * 64 + i * 16 + ln16) * 32 + g * 8];
#pragma unroll
        for (int j = 0; j < 4; ++j)
            bfr[j] = *(const bf16x8*)&Bs[(wn * 64 + j * 16 + ln16) * 32 + g * 8];
#pragma unroll
        for (int i = 0; i < 4; ++i)
#pragma unroll
            for (int j = 0; j < 4; ++j)
                acc[i][j] = __builtin_amdgcn_mfma_f32_16x16x32_bf16(
                    af[i], bfr[j], acc[i][j], 0, 0, 0);
    }

#pragma unroll
    for (int i = 0; i < 4; ++i)
#pragma unroll
        for (int j = 0; j < 4; ++j)
#pragma unroll
            for (int r = 0; r < 4; ++r) {
                int row = m0 + wm * 64 + i * 16 + g * 4 + r;
                int col = n0 + wn * 64 + j * 16 + ln16;
                C[(size_t)row * N + col] = acc[i][j][r];
            }
}

// ---------------------------------------------------------------------------
// Flash attention — round-5: LDS staging RESTORED (round-4's no-staging
// caused 8x XCD L2 re-fetch, FETCH 288 MB, MfmaUtil 6%).
// New vs round-3:
//  (a) XCD-locality block swizzle: lin%8 == h%8, so each XCD's L2 holds
//      exactly 4 (b,h) K/V groups (4 MB, fits) with 16x block reuse.
//  (b) minimal 2-phase pipeline (T3 template, m248v2): double-buffered
//      Ks/Vs, per tile { STAGE next -> buf^1; compute cur; vmcnt(0);
//      barrier } — ONE barrier per tile (was 2) and stage latency hides
//      under the current tile's MFMA+softmax.
// Compute math identical to round-3 (absmax-stable).
// ---------------------------------------------------------------------------
#define P_PITCH  40

#define FA_STAGE(kt, buf) do { \
    gload_lds16(Kbase + (size_t)((kt) + kr0) * 128 + kofs0, Ks + (buf)*4096 + wid * 512); \
    gload_lds16(Kbase + (size_t)((kt) + kr1) * 128 + kofs1, Ks + (buf)*4096 + 2048 + wid * 512); \
    gload_lds16(Vbase + (size_t)vd0 * T_ + (kt) + vofs0,    Vs + (buf)*4096 + wid * 512); \
    gload_lds16(Vbase + (size_t)vd1 * T_ + (kt) + vofs1,    Vs + (buf)*4096 + 2048 + wid * 512); \
} while(0)

__global__ __launch_bounds__(256) void flash_attn(
    const ushort_t* __restrict__ Qh,
    const ushort_t* __restrict__ Kh,
    const ushort_t* __restrict__ Vt,     // [bh][128][T]
    ushort_t* __restrict__ aoh)          // [b*T+t][2048] bf16
{
    __shared__ ushort_t Ks[2 * 32 * 128];
    __shared__ ushort_t Vs[2 * 128 * 32];
    __shared__ ushort_t Pl[4 * 16 * P_PITCH];

    const int tid  = threadIdx.x;
    const int wid  = tid >> 6, lane = tid & 63;
    const int ln16 = lane & 15, g = lane >> 4;

    // XCD-locality swizzle: linear id -> (p, b, h) with lin%8 == h%8
    const int lin = blockIdx.x + (blockIdx.y << 4) + (blockIdx.z << 8);
    const int h = lin & 15;
    const int b = (lin >> 4) & 1;
    const int p = lin >> 5;              // pair index 0..15
    const int bh = b * H_ + h;

    const ushort_t* Kbase = Kh + (size_t)bh * T_ * 128;
    const ushort_t* Vbase = Vt + (size_t)bh * 128 * T_;
    ushort_t* Pw = Pl + wid * 16 * P_PITCH;

    const int sk0 = tid,      sk1 = 256 + tid;
    const int kr0 = sk0 >> 4, kc0 = sk0 & 15;
    const int kr1 = sk1 >> 4, kc1 = sk1 & 15;
    const int vd0 = sk0 >> 2, vg0 = sk0 & 3;
    const int vd1 = sk1 >> 2, vg1 = sk1 & 3;
    const int kofs0 = (kc0 ^ (kr0 & 15)) * 8, kofs1 = (kc1 ^ (kr1 & 15)) * 8;
    const int vofs0 = (vg0 ^ ((vd0 + (vd0 >> 2)) & 3)) * 8;
    const int vofs1 = (vg1 ^ ((vd1 + (vd1 >> 2)) & 3)) * 8;

    bf16x8 bones;
    {
        short o = (ln16 == 0) ? (short)0x3F80 : (short)0;
#pragma unroll
        for (int j = 0; j < 8; ++j) bones[j] = o;
    }

#pragma unroll 1
    for (int ti = 0; ti < 2; ++ti) {
        const int qt = ti ? (31 - p) : p;
        const int q0 = qt * 64;
        const int qw = q0 + wid * 16;

        bf16x8 aq[4];
        {
            const ushort_t* qrow = Qh + ((size_t)bh * T_ + qw + ln16) * 128;
#pragma unroll
            for (int c2 = 0; c2 < 4; ++c2)
                aq[c2] = *(const bf16x8*)(qrow + c2 * 32 + g * 8);
        }

        f32x4 acc[8];
#pragma unroll
        for (int i = 0; i < 8; ++i) acc[i] = (f32x4){0.f, 0.f, 0.f, 0.f};
        f32x4 acc_l = (f32x4){0.f, 0.f, 0.f, 0.f};

        const int nkb  = q0 / 32 + 2;        // block-uniform
        const int qmax = qw + 15;

        // prologue: stage tile0 -> buf0
        FA_STAGE(0, 0);
        asm volatile("s_waitcnt vmcnt(0)" ::: "memory");
        BARS();

#pragma unroll 1
        for (int kb = 0; kb < nkb; ++kb) {
            const int kt = kb * 32;
            if (kb + 1 < nkb) FA_STAGE(kt + 32, (kb + 1) & 1);

            if (kt <= qmax) {
                const int kbuf = (kb & 1) * 4096;

                f32x4 s0 = (f32x4){0.f, 0.f, 0.f, 0.f};
                f32x4 s1 = (f32x4){0.f, 0.f, 0.f, 0.f};
                __builtin_amdgcn_s_setprio(1);
#pragma unroll
                for (int c2 = 0; c2 < 4; ++c2) {
                    int jk = c2 * 4 + g;
                    bf16x8 bk0 = *(const bf16x8*)&Ks[kbuf + (ln16 * 16 + (jk ^ ln16)) * 8];
                    bf16x8 bk1 = *(const bf16x8*)&Ks[kbuf + (256 + ln16 * 16 + (jk ^ ln16)) * 8];
                    s0 = __builtin_amdgcn_mfma_f32_16x16x32_bf16(aq[c2], bk0, s0, 0, 0, 0);
                    s1 = __builtin_amdgcn_mfma_f32_16x16x32_bf16(aq[c2], bk1, s1, 0, 0, 0);
                }
                __builtin_amdgcn_s_setprio(0);

                const bool diag = (kt + 31 > qw);
#pragma unroll
                for (int r2 = 0; r2 < 4; ++r2) {
                    float e0 = __expf(s0[r2] - 12.0f);
                    float e1 = __expf(s1[r2] - 12.0f);
                    if (diag) {
                        int qr = qw + g * 4 + r2;
                        e0 = (kt + ln16      > qr) ? 0.0f : e0;
                        e1 = (kt + 16 + ln16 > qr) ? 0.0f : e1;
                    }
                    int prow = g * 4 + r2;
                    Pw[prow * P_PITCH + ln16]      = f2b(e0);
                    Pw[prow * P_PITCH + 16 + ln16] = f2b(e1);
                }
                __asm__ volatile("s_waitcnt lgkmcnt(0)" ::: "memory");
                bf16x8 ap = *(const bf16x8*)&Pw[ln16 * P_PITCH + g * 8];

                __builtin_amdgcn_s_setprio(1);
#pragma unroll
                for (int cdv = 0; cdv < 8; ++cdv) {
                    int d = cdv * 16 + ln16;
                    bf16x8 bv = *(const bf16x8*)
                        &Vs[kbuf + ((d << 2) + (g ^ ((d + (d >> 2)) & 3))) * 8];
                    acc[cdv] = __builtin_amdgcn_mfma_f32_16x16x32_bf16(ap, bv, acc[cdv], 0, 0, 0);
                }
                acc_l = __builtin_amdgcn_mfma_f32_16x16x32_bf16(ap, bones, acc_l, 0, 0, 0);
                __builtin_amdgcn_s_setprio(0);
            }

            asm volatile("s_waitcnt vmcnt(0)" ::: "memory");
            BARS();
        }

        float invl[4];
#pragma unroll
        for (int r2 = 0; r2 < 4; ++r2)
            invl[r2] = 1.0f / __shfl(acc_l[r2], lane & 48);
#pragma unroll
        for (int cdv = 0; cdv < 8; ++cdv)
#pragma unroll
            for (int r2 = 0; r2 < 4; ++r2) {
                int qr = qw + g * 4 + r2;
                aoh[((size_t)b * T_ + qr) * D_ + h * DH_ + cdv * 16 + ln16] =
                    f2b(acc[cdv][r2] * invl[r2]);
            }
    }
}

// ---------------------------------------------------------------------------
extern "C" void kernel_launch(void* const* d_in, const int* in_sizes, int n_in,
                              void* d_out, int out_size, void* d_ws, size_t ws_size,
                              hipStream_t stream)
{
    const float* x       = (const float*)d_in[0];
    const float* Wq_sem  = (const float*)d_in[1];
    const float* Wk_sem  = (const float*)d_in[2];
    const float* Wq_geo  = (const float*)d_in[3];
    const float* Wk_geo  = (const float*)d_in[4];
    const float* Wv      = (const float*)d_in[5];
    const float* Wo      = (const float*)d_in[6];
    const float* gate    = (const float*)d_in[7];
    const int*   pos_off = (const int*)d_in[8];
    float* out = (float*)d_out;

    const int M = B_ * T_;                       // 4096
    char* ws = (char*)d_ws;
    ushort_t* xh     = (ushort_t*)(ws);                          // [4096][2048] 16MB
    ushort_t* aoh    = xh;                                       // reuse after proj
    ushort_t* Wt_all = (ushort_t*)(ws + (size_t)16 * 1048576);   // [6144][2048] 24MB
    ushort_t* WoT    = (ushort_t*)(ws + (size_t)40 * 1048576);   // [2048][2048] 8MB
    ushort_t* Qh     = (ushort_t*)(ws + (size_t)48 * 1048576);   // 16MB
    ushort_t* Kh     = (ushort_t*)(ws + (size_t)64 * 1048576);   // 16MB
    ushort_t* Vt     = (ushort_t*)(ws + (size_t)80 * 1048576);   // 16MB

    dim3 blk(256);

    convert_x<<<(M * D_) / (256 * 8), blk, 0, stream>>>(x, xh);
    transpose_all<<<dim3(64, 64, 6), blk, 0, stream>>>(
        Wq_sem, Wk_sem, Wq_geo, Wk_geo, Wv, Wo, Wt_all, WoT);

    // 256x256-tile 8-phase pipeline needs 128 KiB dynamic LDS
    hipFuncSetAttribute((const void*)gemm_proj,
                        hipFuncAttributeMaxDynamicSharedMemorySize, 131072);
    gemm_proj<<<dim3(NPROJ / 256, M / 256), dim3(512), 131072, stream>>>(
        xh, Wt_all, gate, pos_off, Qh, Kh, Vt);

    flash_attn<<<dim3(16, H_, B_), blk, 0, stream>>>(Qh, Kh, Vt, aoh);

    gemm_bt_f32<<<dim3(D_ / 128, M / 128), blk, 0, stream>>>(
        aoh, WoT, out, M, D_, D_);
}

// Round 7
// 372.850 us; speedup vs baseline: 1.4319x; 1.0490x over previous
//
#include <hip/hip_runtime.h>
#include <hip/hip_bf16.h>
#include <math.h>

#define B_ 2
#define T_ 2048
#define D_ 2048
#define H_ 16
#define DH_ 128
#define SEM_ 1024
#define GEO_ 1024
#define NPROJ 6144   // 4*1024 (q/k sem/geo) + 2048 (v)

typedef unsigned short ushort_t;
typedef short bf16x8 __attribute__((ext_vector_type(8)));
typedef float f32x4 __attribute__((ext_vector_type(4)));
typedef unsigned short us4 __attribute__((ext_vector_type(4)));
typedef unsigned short us2 __attribute__((ext_vector_type(2)));

static __device__ inline ushort_t f2b(float x) {
    __hip_bfloat16 h = __float2bfloat16(x);
    return *reinterpret_cast<ushort_t*>(&h);
}
static __device__ inline float b2f(ushort_t u) {
    union { unsigned int i; float f; } v; v.i = ((unsigned int)u) << 16; return v.f;
}
static __device__ inline void gload_lds16(const ushort_t* g, ushort_t* l) {
    __builtin_amdgcn_global_load_lds(
        (const __attribute__((address_space(1))) void*)g,
        (__attribute__((address_space(3))) void*)l, 16, 0, 0);
}

#define BARS()  { asm volatile("" ::: "memory"); __builtin_amdgcn_s_barrier(); asm volatile("" ::: "memory"); }
#define WL0()   asm volatile("s_waitcnt lgkmcnt(0)" ::: "memory")
#define WV6()   asm volatile("s_waitcnt vmcnt(6)" ::: "memory")
#define WV4()   asm volatile("s_waitcnt vmcnt(4)" ::: "memory")
#define WV0()   asm volatile("s_waitcnt vmcnt(0)" ::: "memory")

// ---------------------------------------------------------------------------
// x fp32 -> bf16, 8 elems/thread
// ---------------------------------------------------------------------------
__global__ __launch_bounds__(256) void convert_x(
    const float* __restrict__ x, ushort_t* __restrict__ xh)
{
    size_t i = ((size_t)blockIdx.x * 256 + threadIdx.x) * 8;
    float4 a = *(const float4*)&x[i];
    float4 b = *(const float4*)&x[i + 4];
    bf16x8 o;
    o[0] = (short)f2b(a.x); o[1] = (short)f2b(a.y);
    o[2] = (short)f2b(a.z); o[3] = (short)f2b(a.w);
    o[4] = (short)f2b(b.x); o[5] = (short)f2b(b.y);
    o[6] = (short)f2b(b.z); o[7] = (short)f2b(b.w);
    *(bf16x8*)&xh[i] = o;
}

// ---------------------------------------------------------------------------
// All 6 weight transposes in one launch. z selects the weight.
// W[K=2048][N] fp32 -> dst[N][2048] bf16.
// 64x64 tiles — float2 reads (256-B row segments) and ushort2 writes
// (128-B row segments); old 32-wide tiles wrote 64-B segments.
// ---------------------------------------------------------------------------
__global__ __launch_bounds__(256) void transpose_all(
    const float* __restrict__ W0, const float* __restrict__ W1,
    const float* __restrict__ W2, const float* __restrict__ W3,
    const float* __restrict__ W4, const float* __restrict__ W5,
    ushort_t* __restrict__ Wt_all, ushort_t* __restrict__ WoT)
{
    const int z = blockIdx.z;
    const float* W;
    ushort_t* dst;
    int N;
    switch (z) {
        case 0: W = W0; dst = Wt_all;                          N = 1024; break;
        case 1: W = W1; dst = Wt_all + (size_t)1024 * 2048;    N = 1024; break;
        case 2: W = W2; dst = Wt_all + (size_t)2048 * 2048;    N = 1024; break;
        case 3: W = W3; dst = Wt_all + (size_t)3072 * 2048;    N = 1024; break;
        case 4: W = W4; dst = Wt_all + (size_t)4096 * 2048;    N = 2048; break;
        default: W = W5; dst = WoT;                            N = 2048; break;
    }
    const int n0 = blockIdx.x * 64;
    if (n0 >= N) return;
    const int k0 = blockIdx.y * 64;

    __shared__ float tile[64][66];
    const int c2 = (threadIdx.x & 31) * 2;   // n-col pair
    const int r  = threadIdx.x >> 5;         // 0..7
#pragma unroll
    for (int rr = 0; rr < 64; rr += 8) {
        float2 v = *(const float2*)&W[(size_t)(k0 + r + rr) * N + n0 + c2];
        tile[r + rr][c2]     = v.x;
        tile[r + rr][c2 + 1] = v.y;
    }
    __syncthreads();
    const int kc = (threadIdx.x & 31) * 2;   // k-col pair
#pragma unroll
    for (int rr = 0; rr < 64; rr += 8) {
        int nrow = r + rr;
        us2 o;
        o[0] = f2b(tile[kc][nrow]);
        o[1] = f2b(tile[kc + 1][nrow]);
        *(us2*)&dst[(size_t)(n0 + nrow) * 2048 + k0 + kc] = o;
    }
}

// ---------------------------------------------------------------------------
// Projection GEMM — 256x256 tile, BK=64, 8-wave, 8-phase counted-vmcnt
// pipeline (T2 3-bit XOR + T3/T4 + T5), fused RoPE/gate/pack epilogue.
// (unchanged from round-5: 114 µs, FETCH 94 MB, 0 bank conflicts)
// ---------------------------------------------------------------------------
#define LDA8(par, iq, i4, kk) \
    (*(const bf16x8*)&smA[(par)*16384 + (iq)*8192 + aoff + (i4)*1024 + ((kk) ? ca1 : ca0)])
#define LDB8(par, jq, j1, kk) \
    (*(const bf16x8*)&smB[(par)*16384 + (jq)*8192 + boff + (j1)*2048 + ((kk) ? ca1 : ca0)])

#define READ_A(par, iq) \
    aF[0]=LDA8(par,iq,0,0); aF[1]=LDA8(par,iq,0,1); \
    aF[2]=LDA8(par,iq,1,0); aF[3]=LDA8(par,iq,1,1); \
    aF[4]=LDA8(par,iq,2,0); aF[5]=LDA8(par,iq,2,1); \
    aF[6]=LDA8(par,iq,3,0); aF[7]=LDA8(par,iq,3,1);

#define READ_B(par, jq) \
    bF[(jq)*4+0]=LDB8(par,jq,0,0); bF[(jq)*4+1]=LDB8(par,jq,0,1); \
    bF[(jq)*4+2]=LDB8(par,jq,1,0); bF[(jq)*4+3]=LDB8(par,jq,1,1);

#define STAGE_A(h, kt, par) do { \
    const ushort_t* _s = gAbase + (size_t)((h)*128) * 2048 + (kt)*64 + stgoff; \
    ushort_t* _d = smA + (par)*16384 + (h)*8192 + wid*512; \
    gload_lds16(_s, _d); \
    gload_lds16(_s + (size_t)64*2048, _d + 4096); \
} while(0)

#define STAGE_B(h, kt, par) do { \
    const ushort_t* _s = gBbase + (size_t)((h)*128) * 2048 + (kt)*64 + stgoff; \
    ushort_t* _d = smB + (par)*16384 + (h)*8192 + wid*512; \
    gload_lds16(_s, _d); \
    gload_lds16(_s + (size_t)64*2048, _d + 4096); \
} while(0)

#define MM16(iq, jq) do { \
    _Pragma("unroll") \
    for (int i4 = 0; i4 < 4; ++i4) { \
        acc[(iq)*4+i4][(jq)*2+0] = __builtin_amdgcn_mfma_f32_16x16x32_bf16(aF[i4*2+0], bF[(jq)*4+0], acc[(iq)*4+i4][(jq)*2+0], 0, 0, 0); \
        acc[(iq)*4+i4][(jq)*2+0] = __builtin_amdgcn_mfma_f32_16x16x32_bf16(aF[i4*2+1], bF[(jq)*4+1], acc[(iq)*4+i4][(jq)*2+0], 0, 0, 0); \
        acc[(iq)*4+i4][(jq)*2+1] = __builtin_amdgcn_mfma_f32_16x16x32_bf16(aF[i4*2+0], bF[(jq)*4+2], acc[(iq)*4+i4][(jq)*2+1], 0, 0, 0); \
        acc[(iq)*4+i4][(jq)*2+1] = __builtin_amdgcn_mfma_f32_16x16x32_bf16(aF[i4*2+1], bF[(jq)*4+3], acc[(iq)*4+i4][(jq)*2+1], 0, 0, 0); \
    } \
} while(0)

// phase reads are pre-issued at the tail of the previous phase
#define TILE_BODY(par, parn, kt1, kt2) \
    STAGE_A(1, kt1, parn); \
    BARS(); WL0(); \
    __builtin_amdgcn_s_setprio(1); MM16(0, 0); __builtin_amdgcn_s_setprio(0); \
    READ_B(par, 1); \
    BARS(); \
    STAGE_A(0, kt2, par); \
    BARS(); WL0(); \
    __builtin_amdgcn_s_setprio(1); MM16(0, 1); __builtin_amdgcn_s_setprio(0); \
    READ_A(par, 1); \
    BARS(); \
    STAGE_B(0, kt2, par); \
    BARS(); WL0(); \
    __builtin_amdgcn_s_setprio(1); MM16(1, 1); __builtin_amdgcn_s_setprio(0); \
    BARS(); \
    STAGE_B(1, kt2, par); WV6(); \
    BARS(); \
    __builtin_amdgcn_s_setprio(1); MM16(1, 0); __builtin_amdgcn_s_setprio(0); \
    READ_A(parn, 0); READ_B(parn, 0); \
    BARS();

__global__ __launch_bounds__(512, 2) void gemm_proj(
    const ushort_t* __restrict__ A, const ushort_t* __restrict__ Bt,
    const float* __restrict__ gate_logit, const int* __restrict__ pos_off,
    ushort_t* __restrict__ Qh, ushort_t* __restrict__ Kh,
    ushort_t* __restrict__ Vt)
{
    extern __shared__ __align__(16) ushort_t smdyn[];
    ushort_t* smA = smdyn;              // [2 buf][2 half][128][64]
    ushort_t* smB = smdyn + 32768;      // [2 buf][2 half][128][64]

    const int tid  = threadIdx.x;
    const int wid  = tid >> 6, lane = tid & 63;
    const int ln16 = lane & 15, g = lane >> 4;
    const int wm = wid & 1, wn = wid >> 1;
    const int m0 = blockIdx.y * 256, n0 = blockIdx.x * 256;

    const int srow = wid * 8 + (lane >> 3);                    // 0..63
    const int scol = ((lane & 7) ^ (lane >> 3)) * 8;
    const size_t stgoff = (size_t)srow * 2048 + scol;
    const ushort_t* gAbase = A  + (size_t)m0 * 2048;
    const ushort_t* gBbase = Bt + (size_t)n0 * 2048;

    const int cg0 = ln16 & 7;
    const int ca0 = ((g + 0) ^ cg0) * 8;
    const int ca1 = ((g + 4) ^ cg0) * 8;
    const int aoff = wm * 4096 + ln16 * 64;
    const int boff = (wn >> 1) * 4096 + (wn & 1) * 1024 + ln16 * 64;

    f32x4 acc[8][4];
#pragma unroll
    for (int i = 0; i < 8; ++i)
#pragma unroll
        for (int j = 0; j < 4; ++j) acc[i][j] = (f32x4){0.f, 0.f, 0.f, 0.f};
    bf16x8 aF[8], bF[8];

    STAGE_A(0, 0, 0); STAGE_B(0, 0, 0); STAGE_B(1, 0, 0); STAGE_A(1, 0, 0);
    STAGE_A(0, 1, 1); STAGE_B(0, 1, 1); STAGE_B(1, 1, 1);
    WV6();
    BARS();
    READ_A(0, 0); READ_B(0, 0);

#pragma unroll 1
    for (int t = 0; t < 32; t += 2) {
        const int ka1 = t + 1;
        const int ka2 = (t + 2 < 32) ? t + 2 : 31;
        const int kb1 = ka2;
        const int kb2 = (t + 3 < 32) ? t + 3 : 31;
        TILE_BODY(0, 1, ka1, ka2);
        TILE_BODY(1, 0, kb1, kb2);
    }
    asm volatile("s_waitcnt vmcnt(0) lgkmcnt(0)" ::: "memory");  // drain tails

    // ---- fused epilogue -----------------------------------------------
    const int region = n0 >> 10;           // 0 qs | 1 ks | 2 qg | 3 kg | >=4 v
    const int rbase  = m0 + wm * 64 + g * 4;

    if (region <= 1) {
        ushort_t* dst = (region == 0) ? Qh : Kh;
        const int hb  = ((n0 & 1023) >> 6) + (wn >> 1);
        const int d64 = (wn & 1) * 16 + ln16;
        float sc0 = 1.0f, sc1 = 1.0f;
        if (region == 0) {
            sc0 = 0.25f / (1.0f + __expf(-gate_logit[hb]));      // 2*sig*0.125
            sc1 = 0.25f / (1.0f + __expf(-gate_logit[hb + 2]));
        }
#pragma unroll
        for (int i = 0; i < 8; ++i)
#pragma unroll
            for (int r = 0; r < 4; ++r) {
                int row = rbase + (i >> 2) * 128 + (i & 3) * 16 + r;
                int t = row & (T_ - 1), bb = row >> 11;
                size_t b0 = ((size_t)(bb * H_ + hb)     * T_ + t) * 128;
                size_t b1 = ((size_t)(bb * H_ + hb + 2) * T_ + t) * 128;
                dst[b0 + d64]      = f2b(acc[i][0][r] * sc0);
                dst[b0 + d64 + 32] = f2b(acc[i][1][r] * sc0);
                dst[b1 + d64]      = f2b(acc[i][2][r] * sc1);
                dst[b1 + d64 + 32] = f2b(acc[i][3][r] * sc1);
            }
    } else if (region <= 3) {
        ushort_t* dst = (region == 2) ? Qh : Kh;
        const int hb = ((n0 & 1023) >> 6) + (wn >> 1);
        const int ip = (wn & 1) * 16 + ln16;                    // 0..31
        const float invf = __expf(-0.28782313665087625f * (float)ip);
        const float po = (float)(*pos_off);
        float sc0 = 1.0f, sc1 = 1.0f;
        if (region == 2) {
            sc0 = 0.25f * (1.0f - 1.0f / (1.0f + __expf(-gate_logit[hb])));
            sc1 = 0.25f * (1.0f - 1.0f / (1.0f + __expf(-gate_logit[hb + 2])));
        }
#pragma unroll
        for (int i = 0; i < 8; ++i)
#pragma unroll
            for (int r = 0; r < 4; ++r) {
                int row = rbase + (i >> 2) * 128 + (i & 3) * 16 + r;
                int t = row & (T_ - 1), bb = row >> 11;
                float s, c;
                __sincosf(((float)t + po) * invf, &s, &c);
                size_t b0 = ((size_t)(bb * H_ + hb)     * T_ + t) * 128;
                size_t b1 = ((size_t)(bb * H_ + hb + 2) * T_ + t) * 128;
                float x1 = acc[i][0][r], x2 = acc[i][1][r];
                dst[b0 + 64 + ip] = f2b((x1 * c - x2 * s) * sc0);
                dst[b0 + 96 + ip] = f2b((x2 * c + x1 * s) * sc0);
                x1 = acc[i][2][r]; x2 = acc[i][3][r];
                dst[b1 + 64 + ip] = f2b((x1 * c - x2 * s) * sc1);
                dst[b1 + 96 + ip] = f2b((x2 * c + x1 * s) * sc1);
            }
    } else {
        // V region: pack 4 consecutive-t values (r=0..3) into one 8-B store
        const int hb = (n0 - 4096) >> 7;
        const int db = (wn >> 1) * 64 + (wn & 1) * 16 + ln16;   // 0..127
#pragma unroll
        for (int i = 0; i < 8; ++i) {
            int row0 = rbase + (i >> 2) * 128 + (i & 3) * 16;   // r = 0
            int t0 = row0 & (T_ - 1), bb = row0 >> 11;
#pragma unroll
            for (int j = 0; j < 4; ++j) {
                us4 v;
                v[0] = f2b(acc[i][j][0]); v[1] = f2b(acc[i][j][1]);
                v[2] = f2b(acc[i][j][2]); v[3] = f2b(acc[i][j][3]);
                int hh = hb + (j >> 1);
                int dd = db + (j & 1) * 32;
                *(us4*)&Vt[((size_t)(bb * H_ + hh) * DH_ + dd) * T_ + t0] = v;
            }
        }
    }
}

// ---------------------------------------------------------------------------
// Generic bf16 MFMA GEMM, fp32 out — used for Wo.
// Counted-vmcnt double-buffer (T3/T4 minimal form): raw s_barrier,
// vmcnt(4) instead of the __syncthreads() full drain; stage(t+2) issued
// after the barrier ending all reads of buf[t&1]. Accumulation order
// unchanged (bit-identical output).
// ---------------------------------------------------------------------------
#define BT_STAGE(k, buf) do { \
    gload_lds16(gA + (k),       As + (buf)*4096 + wid*1024); \
    gload_lds16(gA + (k) + K16, As + (buf)*4096 + wid*1024 + 512); \
    gload_lds16(gB + (k),       Bs + (buf)*4096 + wid*1024); \
    gload_lds16(gB + (k) + K16, Bs + (buf)*4096 + wid*1024 + 512); \
} while(0)

__global__ __launch_bounds__(256) void gemm_bt_f32(
    const ushort_t* __restrict__ A, const ushort_t* __restrict__ Bt,
    float* __restrict__ C, int M, int N, int K)
{
    __shared__ ushort_t As[2 * 128 * 32];
    __shared__ ushort_t Bs[2 * 128 * 32];

    const int tid  = threadIdx.x;
    const int wid  = tid >> 6, lane = tid & 63;
    const int ln16 = lane & 15, g = lane >> 4;
    const int wm = wid & 1, wn = wid >> 1;
    const int m0 = blockIdx.y * 128, n0 = blockIdx.x * 128;

    const int lrow = lane >> 2;
    const int lc8  = (lane & 3) * 8;
    const ushort_t* gA = A  + (size_t)(m0 + wid * 32 + lrow) * K + lc8;
    const ushort_t* gB = Bt + (size_t)(n0 + wid * 32 + lrow) * K + lc8;
    const size_t K16 = (size_t)16 * K;

    f32x4 acc[4][4];
#pragma unroll
    for (int i = 0; i < 4; ++i)
#pragma unroll
        for (int j = 0; j < 4; ++j) acc[i][j] = (f32x4){0.f, 0.f, 0.f, 0.f};

    const int nk = K >> 5;
    BT_STAGE(0, 0);
    BT_STAGE(32, 1);

#pragma unroll 1
    for (int kb = 0; kb < nk; ++kb) {
        if (kb + 1 < nk) { WV4(); } else { WV0(); }
        BARS();

        const int bufo = (kb & 1) * 4096;
        bf16x8 af[4], bfr[4];
#pragma unroll
        for (int i = 0; i < 4; ++i)
            af[i] = *(const bf16x8*)&As[bufo + (wm * 64 + i * 16 + ln16) * 32 + g * 8];
#pragma unroll
        for (int j = 0; j < 4; ++j)
            bfr[j] = *(const bf16x8*)&Bs[bufo + (wn * 64 + j * 16 + ln16) * 32 + g * 8];
        __builtin_amdgcn_s_setprio(1);
#pragma unroll
        for (int i = 0; i < 4; ++i)
#pragma unroll
            for (int j = 0; j < 4; ++j)
                acc[i][j] = __builtin_amdgcn_mfma_f32_16x16x32_bf16(
                    af[i], bfr[j], acc[i][j], 0, 0, 0);
        __builtin_amdgcn_s_setprio(0);
        WL0();
        BARS();

        if (kb + 2 < nk) BT_STAGE((size_t)(kb + 2) * 32, kb & 1);
    }

#pragma unroll
    for (int i = 0; i < 4; ++i)
#pragma unroll
        for (int j = 0; j < 4; ++j)
#pragma unroll
            for (int r = 0; r < 4; ++r) {
                int row = m0 + wm * 64 + i * 16 + g * 4 + r;
                int col = n0 + wn * 64 + j * 16 + ln16;
                C[(size_t)row * N + col] = acc[i][j][r];
            }
}

// ---------------------------------------------------------------------------
// Flash attention — counted-vmcnt pipeline. Per iter:
//   { vmcnt(4) [stage(t) done, stage(t+1) in flight]; bar; compute(t);
//     bar; stage(t+2) -> buf[t&1] }
// — no mid-loop vmcnt(0) drain (only the final iteration drains). stage(t+2)
// is issued strictly after the barrier ending all reads of buf[t&1].
// XCD-locality swizzle (lin%8 == h%8) kept from round-5.
// ---------------------------------------------------------------------------
#define P_PITCH  40

#define FA_STAGE(kt, buf) do { \
    gload_lds16(Kbase + (size_t)((kt) + kr0) * 128 + kofs0, Ks + (buf)*4096 + wid * 512); \
    gload_lds16(Kbase + (size_t)((kt) + kr1) * 128 + kofs1, Ks + (buf)*4096 + 2048 + wid * 512); \
    gload_lds16(Vbase + (size_t)vd0 * T_ + (kt) + vofs0,    Vs + (buf)*4096 + wid * 512); \
    gload_lds16(Vbase + (size_t)vd1 * T_ + (kt) + vofs1,    Vs + (buf)*4096 + 2048 + wid * 512); \
} while(0)

__global__ __launch_bounds__(256) void flash_attn(
    const ushort_t* __restrict__ Qh,
    const ushort_t* __restrict__ Kh,
    const ushort_t* __restrict__ Vt,     // [bh][128][T]
    ushort_t* __restrict__ aoh)          // [b*T+t][2048] bf16
{
    __shared__ ushort_t Ks[2 * 32 * 128];
    __shared__ ushort_t Vs[2 * 128 * 32];
    __shared__ ushort_t Pl[4 * 16 * P_PITCH];

    const int tid  = threadIdx.x;
    const int wid  = tid >> 6, lane = tid & 63;
    const int ln16 = lane & 15, g = lane >> 4;

    // XCD-locality swizzle: linear id -> (p, b, h) with lin%8 == h%8
    const int lin = blockIdx.x + (blockIdx.y << 4) + (blockIdx.z << 8);
    const int h = lin & 15;
    const int b = (lin >> 4) & 1;
    const int p = lin >> 5;              // pair index 0..15
    const int bh = b * H_ + h;

    const ushort_t* Kbase = Kh + (size_t)bh * T_ * 128;
    const ushort_t* Vbase = Vt + (size_t)bh * 128 * T_;
    ushort_t* Pw = Pl + wid * 16 * P_PITCH;

    const int sk0 = tid,      sk1 = 256 + tid;
    const int kr0 = sk0 >> 4, kc0 = sk0 & 15;
    const int kr1 = sk1 >> 4, kc1 = sk1 & 15;
    const int vd0 = sk0 >> 2, vg0 = sk0 & 3;
    const int vd1 = sk1 >> 2, vg1 = sk1 & 3;
    const int kofs0 = (kc0 ^ (kr0 & 15)) * 8, kofs1 = (kc1 ^ (kr1 & 15)) * 8;
    const int vofs0 = (vg0 ^ ((vd0 + (vd0 >> 2)) & 3)) * 8;
    const int vofs1 = (vg1 ^ ((vd1 + (vd1 >> 2)) & 3)) * 8;

    bf16x8 bones;
    {
        short o = (ln16 == 0) ? (short)0x3F80 : (short)0;
#pragma unroll
        for (int j = 0; j < 8; ++j) bones[j] = o;
    }

#pragma unroll 1
    for (int ti = 0; ti < 2; ++ti) {
        const int qt = ti ? (31 - p) : p;
        const int q0 = qt * 64;
        const int qw = q0 + wid * 16;

        bf16x8 aq[4];
        {
            const ushort_t* qrow = Qh + ((size_t)bh * T_ + qw + ln16) * 128;
#pragma unroll
            for (int c2 = 0; c2 < 4; ++c2)
                aq[c2] = *(const bf16x8*)(qrow + c2 * 32 + g * 8);
        }

        f32x4 acc[8];
#pragma unroll
        for (int i = 0; i < 8; ++i) acc[i] = (f32x4){0.f, 0.f, 0.f, 0.f};
        f32x4 acc_l = (f32x4){0.f, 0.f, 0.f, 0.f};

        const int nkb  = q0 / 32 + 2;        // block-uniform, >= 2
        const int qmax = qw + 15;

        // prologue: two tiles in flight
        FA_STAGE(0, 0);
        FA_STAGE(32, 1);

#pragma unroll 1
        for (int kb = 0; kb < nkb; ++kb) {
            const int kt = kb * 32;
            if (kb + 1 < nkb) { WV4(); } else { WV0(); }
            BARS();

            if (kt <= qmax) {
                const int kbuf = (kb & 1) * 4096;

                f32x4 s0 = (f32x4){0.f, 0.f, 0.f, 0.f};
                f32x4 s1 = (f32x4){0.f, 0.f, 0.f, 0.f};
                __builtin_amdgcn_s_setprio(1);
#pragma unroll
                for (int c2 = 0; c2 < 4; ++c2) {
                    int jk = c2 * 4 + g;
                    bf16x8 bk0 = *(const bf16x8*)&Ks[kbuf + (ln16 * 16 + (jk ^ ln16)) * 8];
                    bf16x8 bk1 = *(const bf16x8*)&Ks[kbuf + (256 + ln16 * 16 + (jk ^ ln16)) * 8];
                    s0 = __builtin_amdgcn_mfma_f32_16x16x32_bf16(aq[c2], bk0, s0, 0, 0, 0);
                    s1 = __builtin_amdgcn_mfma_f32_16x16x32_bf16(aq[c2], bk1, s1, 0, 0, 0);
                }
                __builtin_amdgcn_s_setprio(0);

                const bool diag = (kt + 31 > qw);
#pragma unroll
                for (int r2 = 0; r2 < 4; ++r2) {
                    float e0 = __expf(s0[r2] - 12.0f);
                    float e1 = __expf(s1[r2] - 12.0f);
                    if (diag) {
                        int qr = qw + g * 4 + r2;
                        e0 = (kt + ln16      > qr) ? 0.0f : e0;
                        e1 = (kt + 16 + ln16 > qr) ? 0.0f : e1;
                    }
                    int prow = g * 4 + r2;
                    Pw[prow * P_PITCH + ln16]      = f2b(e0);
                    Pw[prow * P_PITCH + 16 + ln16] = f2b(e1);
                }
                __asm__ volatile("s_waitcnt lgkmcnt(0)" ::: "memory");
                bf16x8 ap = *(const bf16x8*)&Pw[ln16 * P_PITCH + g * 8];

                __builtin_amdgcn_s_setprio(1);
#pragma unroll
                for (int cdv = 0; cdv < 8; ++cdv) {
                    int d = cdv * 16 + ln16;
                    bf16x8 bv = *(const bf16x8*)
                        &Vs[kbuf + ((d << 2) + (g ^ ((d + (d >> 2)) & 3))) * 8];
                    acc[cdv] = __builtin_amdgcn_mfma_f32_16x16x32_bf16(ap, bv, acc[cdv], 0, 0, 0);
                }
                acc_l = __builtin_amdgcn_mfma_f32_16x16x32_bf16(ap, bones, acc_l, 0, 0, 0);
                __builtin_amdgcn_s_setprio(0);
                WL0();
            }

            BARS();
            if (kb + 2 < nkb) FA_STAGE(kt + 64, kb & 1);
        }

        float invl[4];
#pragma unroll
        for (int r2 = 0; r2 < 4; ++r2)
            invl[r2] = 1.0f / __shfl(acc_l[r2], lane & 48);
#pragma unroll
        for (int cdv = 0; cdv < 8; ++cdv)
#pragma unroll
            for (int r2 = 0; r2 < 4; ++r2) {
                int qr = qw + g * 4 + r2;
                aoh[((size_t)b * T_ + qr) * D_ + h * DH_ + cdv * 16 + ln16] =
                    f2b(acc[cdv][r2] * invl[r2]);
            }
    }
}

// ---------------------------------------------------------------------------
extern "C" void kernel_launch(void* const* d_in, const int* in_sizes, int n_in,
                              void* d_out, int out_size, void* d_ws, size_t ws_size,
                              hipStream_t stream)
{
    const float* x       = (const float*)d_in[0];
    const float* Wq_sem  = (const float*)d_in[1];
    const float* Wk_sem  = (const float*)d_in[2];
    const float* Wq_geo  = (const float*)d_in[3];
    const float* Wk_geo  = (const float*)d_in[4];
    const float* Wv      = (const float*)d_in[5];
    const float* Wo      = (const float*)d_in[6];
    const float* gate    = (const float*)d_in[7];
    const int*   pos_off = (const int*)d_in[8];
    float* out = (float*)d_out;

    const int M = B_ * T_;                       // 4096
    char* ws = (char*)d_ws;
    ushort_t* xh     = (ushort_t*)(ws);                          // [4096][2048] 16MB
    ushort_t* aoh    = xh;                                       // reuse after proj
    ushort_t* Wt_all = (ushort_t*)(ws + (size_t)16 * 1048576);   // [6144][2048] 24MB
    ushort_t* WoT    = (ushort_t*)(ws + (size_t)40 * 1048576);   // [2048][2048] 8MB
    ushort_t* Qh     = (ushort_t*)(ws + (size_t)48 * 1048576);   // 16MB
    ushort_t* Kh     = (ushort_t*)(ws + (size_t)64 * 1048576);   // 16MB
    ushort_t* Vt     = (ushort_t*)(ws + (size_t)80 * 1048576);   // 16MB

    dim3 blk(256);

    convert_x<<<(M * D_) / (256 * 8), blk, 0, stream>>>(x, xh);
    transpose_all<<<dim3(32, 32, 6), blk, 0, stream>>>(
        Wq_sem, Wk_sem, Wq_geo, Wk_geo, Wv, Wo, Wt_all, WoT);

    // 256x256-tile 8-phase pipeline needs 128 KiB dynamic LDS
    hipFuncSetAttribute((const void*)gemm_proj,
                        hipFuncAttributeMaxDynamicSharedMemorySize, 131072);
    gemm_proj<<<dim3(NPROJ / 256, M / 256), dim3(512), 131072, stream>>>(
        xh, Wt_all, gate, pos_off, Qh, Kh, Vt);

    flash_attn<<<dim3(16, H_, B_), blk, 0, stream>>>(Qh, Kh, Vt, aoh);

    gemm_bt_f32<<<dim3(D_ / 128, M / 128), blk, 0, stream>>>(
        aoh, WoT, out, M, D_, D_);
}